// Round 11
// baseline (224.919 us; speedup 1.0000x reference)
//
#include <hip/hip_runtime.h>
#include <hip/hip_fp16.h>

// Ontomap: loss = sum((n2f@n_e - f_e)^2) + sum((m2f@m_e - f_e)^2)
// B = 1,048,576, D = 64.
// Round 11: R10 skeleton (fp8 tables, K-remap k=hi*32+t*8+j dwordx4 gathers,
// sequential 16-reg accumulator tiles) + DOUBLE-BUFFERED FRAGMENT PREFETCH
// (distance 2): loop unrolled x2 with two explicit scalar staging sets; loads
// for iter it+2 issue right after iter it's MFMAs consume their regs ->
// ~2 iterations of flight per load. R10 was MLP-starved (6 loads in flight,
// consumed same iteration; R2's 48-deep f-phase sustained 5x the tx rate).
// No structs / no conditional dataflow (R9's spill trigger): indices clamped,
// tail gathers redundantly refetch L1-hot rows.

typedef _Float16 half8 __attribute__((ext_vector_type(8)));
typedef __fp16  fp16x2 __attribute__((ext_vector_type(2)));
typedef float floatx16 __attribute__((ext_vector_type(16)));

#define NBLOCKS 1024
#define SPB 128                 // samples per block: 4 waves * 32
#define NCI_ELEMS 9600000       // 150000 * 64
#define FMA_ELEMS 6400000       // 100000 * 64

__device__ inline half8 cvt8(float4 a, float4 b) {
    union { half8 h; fp16x2 h2[4]; } u;
    u.h2[0] = __builtin_amdgcn_cvt_pkrtz(a.x, a.y);
    u.h2[1] = __builtin_amdgcn_cvt_pkrtz(a.z, a.w);
    u.h2[2] = __builtin_amdgcn_cvt_pkrtz(b.x, b.y);
    u.h2[3] = __builtin_amdgcn_cvt_pkrtz(b.z, b.w);
    return u.h;
}

__device__ inline uint2 pack4(float4 v) {
    union { fp16x2 h2[2]; uint2 u; } p;
    p.h2[0] = __builtin_amdgcn_cvt_pkrtz(v.x, v.y);
    p.h2[1] = __builtin_amdgcn_cvt_pkrtz(v.z, v.w);
    return p.u;
}

// 8 fp32 -> 8 fp8-e4m3 bytes (ascending order).
__device__ inline uint2 pack8_fp8(float4 a, float4 b) {
    int lo = 0, hi = 0;
    lo = __builtin_amdgcn_cvt_pk_fp8_f32(a.x, a.y, lo, false);
    lo = __builtin_amdgcn_cvt_pk_fp8_f32(a.z, a.w, lo, true);
    hi = __builtin_amdgcn_cvt_pk_fp8_f32(b.x, b.y, hi, false);
    hi = __builtin_amdgcn_cvt_pk_fp8_f32(b.z, b.w, hi, true);
    uint2 r; r.x = (unsigned)lo; r.y = (unsigned)hi; return r;
}

__device__ inline long pack8_fp8_l(const float* p) {
    uint2 b = pack8_fp8(*(const float4*)p, *(const float4*)(p + 4));
    return (long)(((unsigned long)b.y << 32) | b.x);
}

// ---- streaming conversion: both tables -> fp8, into workspace.
__global__ __launch_bounds__(256) void convert_kernel(
    const float4* __restrict__ nci, const float4* __restrict__ fma,
    uint2* __restrict__ nci8, uint2* __restrict__ fma8)
{
    const int stride = gridDim.x * blockDim.x;
    const int tid = blockIdx.x * blockDim.x + threadIdx.x;
    for (int i = tid; i < NCI_ELEMS / 8; i += stride)
        nci8[i] = pack8_fp8(nci[2 * i], nci[2 * i + 1]);
    for (int i = tid; i < FMA_ELEMS / 8; i += stride)
        fma8[i] = pack8_fp8(fma[2 * i], fma[2 * i + 1]);
}

// Issue the 6 independent dwordx4 gathers for one sample-set.
#define GATHER(iN, iM, iF, n01, n23, f01, f23, m01, m23)                     \
    {                                                                        \
        const unsigned char* pn_ = nci8 + (long)(iN) * 64 + hoff;            \
        const unsigned char* pf_ = fma8 + (long)(iF) * 64 + hoff;            \
        const unsigned char* pm_ = nci8 + (long)(iM) * 64 + hoff;            \
        n01 = *(const ulonglong2*)pn_;                                       \
        n23 = *(const ulonglong2*)(pn_ + 16);                                \
        f01 = *(const ulonglong2*)pf_;                                       \
        f23 = *(const ulonglong2*)(pf_ + 16);                                \
        m01 = *(const ulonglong2*)pm_;                                       \
        m23 = *(const ulonglong2*)(pm_ + 16);                                \
    }

// 4 sequential output tiles (one 16-reg accumulator live at a time).
#define COMPUTE_TILES(n01, n23, f01, f23, m01, m23)                          \
    {                                                                        \
        const long An_[4] = {(long)(n01).x, (long)(n01).y,                   \
                             (long)(n23).x, (long)(n23).y};                  \
        const long Ff_[4] = {(long)(f01).x, (long)(f01).y,                   \
                             (long)(f23).x, (long)(f23).y};                  \
        const long Am_[4] = {(long)(m01).x, (long)(m01).y,                   \
                             (long)(m23).x, (long)(m23).y};                  \
        {                                                                    \
            floatx16 a{};                                                    \
            _Pragma("unroll")                                                \
            for (int t = 0; t < 4; ++t)                                      \
                a = __builtin_amdgcn_mfma_f32_32x32x16_fp8_fp8(An_[t], Bn[0][t], a, 0, 0, 0); \
            _Pragma("unroll")                                                \
            for (int t = 0; t < 4; ++t)                                      \
                a = __builtin_amdgcn_mfma_f32_32x32x16_fp8_fp8(Ff_[t], If0[t], a, 0, 0, 0);   \
            _Pragma("unroll")                                                \
            for (int r = 0; r < 16; ++r) loss = fmaf(a[r], a[r], loss);      \
        }                                                                    \
        {                                                                    \
            floatx16 a{};                                                    \
            _Pragma("unroll")                                                \
            for (int t = 0; t < 4; ++t)                                      \
                a = __builtin_amdgcn_mfma_f32_32x32x16_fp8_fp8(An_[t], Bn[1][t], a, 0, 0, 0); \
            _Pragma("unroll")                                                \
            for (int t = 0; t < 4; ++t)                                      \
                a = __builtin_amdgcn_mfma_f32_32x32x16_fp8_fp8(Ff_[t], If1[t], a, 0, 0, 0);   \
            _Pragma("unroll")                                                \
            for (int r = 0; r < 16; ++r) loss = fmaf(a[r], a[r], loss);      \
        }                                                                    \
        {                                                                    \
            floatx16 a{};                                                    \
            _Pragma("unroll")                                                \
            for (int t = 0; t < 4; ++t)                                      \
                a = __builtin_amdgcn_mfma_f32_32x32x16_fp8_fp8(Am_[t], Bm[0][t], a, 0, 0, 0); \
            _Pragma("unroll")                                                \
            for (int t = 0; t < 4; ++t)                                      \
                a = __builtin_amdgcn_mfma_f32_32x32x16_fp8_fp8(Ff_[t], If0[t], a, 0, 0, 0);   \
            _Pragma("unroll")                                                \
            for (int r = 0; r < 16; ++r) loss = fmaf(a[r], a[r], loss);      \
        }                                                                    \
        {                                                                    \
            floatx16 a{};                                                    \
            _Pragma("unroll")                                                \
            for (int t = 0; t < 4; ++t)                                      \
                a = __builtin_amdgcn_mfma_f32_32x32x16_fp8_fp8(Am_[t], Bm[1][t], a, 0, 0, 0); \
            _Pragma("unroll")                                                \
            for (int t = 0; t < 4; ++t)                                      \
                a = __builtin_amdgcn_mfma_f32_32x32x16_fp8_fp8(Ff_[t], If1[t], a, 0, 0, 0);   \
            _Pragma("unroll")                                                \
            for (int r = 0; r < 16; ++r) loss = fmaf(a[r], a[r], loss);      \
        }                                                                    \
    }

// ---- main kernel.
__global__ __launch_bounds__(256, 4) void ontomap_kernel_q(
    const int* __restrict__ pos_n, const int* __restrict__ pos_m,
    const int* __restrict__ pos_f,
    const unsigned char* __restrict__ nci8, const unsigned char* __restrict__ fma8,
    const float* __restrict__ n2f, const float* __restrict__ m2f,
    float* __restrict__ out, int iters)
{
    const int lane = threadIdx.x & 63;
    const int wave = threadIdx.x >> 6;
    const int l31  = lane & 31;
    const int hi   = lane >> 5;
    const int hoff = hi * 32;     // this lane's contiguous 32-byte half-row

    // B fragments under the K-remap k = hoff + t*8 + j.
    long Bn[2][4], Bm[2][4];
#pragma unroll
    for (int nt = 0; nt < 2; ++nt) {
#pragma unroll
        for (int t = 0; t < 4; ++t) {
            Bn[nt][t] = pack8_fp8_l(n2f + (nt * 32 + l31) * 64 + hoff + t * 8);
            Bm[nt][t] = pack8_fp8_l(m2f + (nt * 32 + l31) * 64 + hoff + t * 8);
        }
    }

    // -I fragments (fp8 0xB8 = -1.0 e4m3), verified in rounds 9/10.
    long If0[4], If1[4];
#pragma unroll
    for (int t = 0; t < 4; ++t) {
        const unsigned j = (unsigned)(l31 - t * 8);
        const long pat = (j < 8) ? (long)(0xB8ULL << (8 * j)) : 0L;
        If0[t] = hi ? 0L : pat;
        If1[t] = hi ? pat : 0L;
    }

    float loss = 0.0f;

    const int base  = blockIdx.x * SPB + wave * 32 + l31;
    const int istep = NBLOCKS * SPB;
    const int last  = iters - 1;

    // ---- pipeline fill: stage sets 0 and 1; indices for 2 and 3.
    int iNa = pos_n[base], iMa = pos_m[base], iFa = pos_f[base];
    int s1 = istep + base;
    int iNb = pos_n[s1], iMb = pos_m[s1], iFb = pos_f[s1];

    ulonglong2 An01, An23, Af01, Af23, Am01, Am23;   // set 0
    ulonglong2 Bn01, Bn23, Bf01, Bf23, Bm01, Bm23;   // set 1
    GATHER(iNa, iMa, iFa, An01, An23, Af01, Af23, Am01, Am23);
    GATHER(iNb, iMb, iFb, Bn01, Bn23, Bf01, Bf23, Bm01, Bm23);

    {
        int s = min(2, last) * istep + base;
        iNa = pos_n[s]; iMa = pos_m[s]; iFa = pos_f[s];
        s = min(3, last) * istep + base;
        iNb = pos_n[s]; iMb = pos_m[s]; iFb = pos_f[s];
    }

#pragma unroll 1
    for (int it = 0; it < iters; it += 2) {
        // even iteration: compute set 0, then refill it for it+2.
        COMPUTE_TILES(An01, An23, Af01, Af23, Am01, Am23);
        GATHER(iNa, iMa, iFa, An01, An23, Af01, Af23, Am01, Am23);
        {
            int s = min(it + 4, last) * istep + base;
            iNa = pos_n[s]; iMa = pos_m[s]; iFa = pos_f[s];
        }
        // odd iteration: compute set 1, refill for it+3.
        COMPUTE_TILES(Bn01, Bn23, Bf01, Bf23, Bm01, Bm23);
        GATHER(iNb, iMb, iFb, Bn01, Bn23, Bf01, Bf23, Bm01, Bm23);
        {
            int s = min(it + 5, last) * istep + base;
            iNb = pos_n[s]; iMb = pos_m[s]; iFb = pos_f[s];
        }
    }

#pragma unroll
    for (int o = 32; o > 0; o >>= 1) loss += __shfl_xor(loss, o, 64);
    if (lane == 0) atomicAdd(out, loss);
}

// ---- fallback: fp32 tables with LDS staging (round-4 style), if ws too small.
#define ROW_BYTES 144
__global__ __launch_bounds__(256, 2) void ontomap_kernel_f32(
    const int* __restrict__ pos_n, const int* __restrict__ pos_m,
    const int* __restrict__ pos_f,
    const float* __restrict__ nci, const float* __restrict__ fma_emb,
    const float* __restrict__ n2f, const float* __restrict__ m2f,
    float* __restrict__ out, int iters)
{
    __shared__ char lds[4 * 2 * 32 * ROW_BYTES];

    const int lane = threadIdx.x & 63;
    const int wave = threadIdx.x >> 6;
    const int l31  = lane & 31;
    const int hi   = lane >> 5;
    const int kbase = hi * 8;
    const int srow   = lane >> 4;
    const int schunk = lane & 15;

    char* const nbase = lds + wave * (2 * 32 * ROW_BYTES);
    char* const mbase = nbase + 32 * ROW_BYTES;

    half8 Bn[2][4], Bm[2][4];
#pragma unroll
    for (int nt = 0; nt < 2; ++nt) {
#pragma unroll
        for (int t = 0; t < 4; ++t) {
            const float* p = n2f + (nt * 32 + l31) * 64 + t * 16 + kbase;
            Bn[nt][t] = cvt8(*(const float4*)p, *(const float4*)(p + 4));
            const float* q = m2f + (nt * 32 + l31) * 64 + t * 16 + kbase;
            Bm[nt][t] = cvt8(*(const float4*)q, *(const float4*)(q + 4));
        }
    }

    float loss = 0.0f;
    int in_, im_, if_;
    {
        int s = blockIdx.x * SPB + wave * 32 + l31;
        in_ = pos_n[s]; im_ = pos_m[s]; if_ = pos_f[s];
    }

#pragma unroll 1
    for (int it = 0; it < iters; ++it) {
        const int in0 = in_, im0 = im_, if0 = if_;
        if (it + 1 < iters) {
            int s = ((it + 1) * NBLOCKS + blockIdx.x) * SPB + wave * 32 + l31;
            in_ = pos_n[s]; im_ = pos_m[s]; if_ = pos_f[s];
        }

#pragma unroll
        for (int i = 0; i < 8; ++i) {
            const int rl = i * 4 + srow;
            const int rn = __shfl(in0, rl, 64);
            float4 v = ((const float4*)(nci + (long)rn * 64))[schunk];
            *(uint2*)(nbase + rl * ROW_BYTES + schunk * 8) = pack4(v);
            const int rm = __shfl(im0, rl, 64);
            float4 w = ((const float4*)(nci + (long)rm * 64))[schunk];
            *(uint2*)(mbase + rl * ROW_BYTES + schunk * 8) = pack4(w);
        }
        asm volatile("" ::: "memory");

        floatx16 aN0{}, aN1{}, aM0{}, aM1{};
#pragma unroll
        for (int t = 0; t < 4; ++t) {
            half8 aF = *(const half8*)(nbase + l31 * ROW_BYTES + t * 32 + hi * 16);
            aN0 = __builtin_amdgcn_mfma_f32_32x32x16_f16(aF, Bn[0][t], aN0, 0, 0, 0);
            aN1 = __builtin_amdgcn_mfma_f32_32x32x16_f16(aF, Bn[1][t], aN1, 0, 0, 0);
            half8 bF = *(const half8*)(mbase + l31 * ROW_BYTES + t * 32 + hi * 16);
            aM0 = __builtin_amdgcn_mfma_f32_32x32x16_f16(bF, Bm[0][t], aM0, 0, 0, 0);
            aM1 = __builtin_amdgcn_mfma_f32_32x32x16_f16(bF, Bm[1][t], aM1, 0, 0, 0);
        }

#pragma unroll
        for (int r = 0; r < 16; ++r) {
            const int mrow = (r & 3) + 8 * (r >> 2) + 4 * hi;
            const int fid  = __shfl(if0, mrow, 64);
            const float* pf = fma_emb + (long)fid * 64 + l31;
            const float f0 = pf[0];
            const float f1 = pf[32];
            float d;
            d = aN0[r] - f0; loss = fmaf(d, d, loss);
            d = aM0[r] - f0; loss = fmaf(d, d, loss);
            d = aN1[r] - f1; loss = fmaf(d, d, loss);
            d = aM1[r] - f1; loss = fmaf(d, d, loss);
        }
    }

#pragma unroll
    for (int o = 32; o > 0; o >>= 1) loss += __shfl_xor(loss, o, 64);
    if (lane == 0) atomicAdd(out, loss);
}

extern "C" void kernel_launch(void* const* d_in, const int* in_sizes, int n_in,
                              void* d_out, int out_size, void* d_ws, size_t ws_size,
                              hipStream_t stream) {
    const int*   pos_n   = (const int*)d_in[0];
    const int*   pos_m   = (const int*)d_in[1];
    const int*   pos_f   = (const int*)d_in[2];
    const float* nci_emb = (const float*)d_in[3];
    const float* fma_emb = (const float*)d_in[4];
    const float* n2f_mat = (const float*)d_in[5];
    const float* m2f_mat = (const float*)d_in[6];
    float* out = (float*)d_out;

    const int B = in_sizes[0];
    const int iters = B / (NBLOCKS * SPB);  // 1,048,576 -> 8

    (void)hipMemsetAsync(out, 0, sizeof(float), stream);

    const size_t need = (size_t)NCI_ELEMS + (size_t)FMA_ELEMS;  // 16 MB
    if (ws_size >= need) {
        unsigned char* nci8 = (unsigned char*)d_ws;
        unsigned char* fma8 = nci8 + NCI_ELEMS;   // 9,600,000 is 64B-aligned
        convert_kernel<<<2048, 256, 0, stream>>>(
            (const float4*)nci_emb, (const float4*)fma_emb,
            (uint2*)nci8, (uint2*)fma8);
        ontomap_kernel_q<<<NBLOCKS, 256, 0, stream>>>(
            pos_n, pos_m, pos_f, nci8, fma8, n2f_mat, m2f_mat, out, iters);
    } else {
        ontomap_kernel_f32<<<NBLOCKS, 256, 0, stream>>>(
            pos_n, pos_m, pos_f, nci_emb, fma_emb, n2f_mat, m2f_mat, out, iters);
    }
}

// Round 12
// 189.544 us; speedup vs baseline: 1.1866x; 1.1866x over previous
//
#include <hip/hip_runtime.h>
#include <hip/hip_fp16.h>

// Ontomap: loss = sum((n2f@n_e - f_e)^2) + sum((m2f@m_e - f_e)^2)
// B = 1,048,576, D = 64.
// Round 12: identical dataflow to round 11 (fp8 tables, K-remap dwordx4
// gathers, sequential 16-reg accumulator tiles, distance-2 double-buffered
// register prefetch) with __launch_bounds__(256,3) instead of (256,4).
// R11 post-mortem: at (256,4) the budget is 128 regs/wave and the 4 MFMA
// accumulator chains already pin 64 AGPRs (unified file) + 64 arch VGPRs =
// exactly 128 -> the 24 staging regs spilled to scratch (WRITE_SIZE 42 MB).
// (256,3) gives 170 regs/wave: staging fits, spills gone, and each gather
// gets ~1.5 iterations of flight time.

typedef _Float16 half8 __attribute__((ext_vector_type(8)));
typedef __fp16  fp16x2 __attribute__((ext_vector_type(2)));
typedef float floatx16 __attribute__((ext_vector_type(16)));

#define NBLOCKS 1024
#define SPB 128                 // samples per block: 4 waves * 32
#define NCI_ELEMS 9600000       // 150000 * 64
#define FMA_ELEMS 6400000       // 100000 * 64

__device__ inline half8 cvt8(float4 a, float4 b) {
    union { half8 h; fp16x2 h2[4]; } u;
    u.h2[0] = __builtin_amdgcn_cvt_pkrtz(a.x, a.y);
    u.h2[1] = __builtin_amdgcn_cvt_pkrtz(a.z, a.w);
    u.h2[2] = __builtin_amdgcn_cvt_pkrtz(b.x, b.y);
    u.h2[3] = __builtin_amdgcn_cvt_pkrtz(b.z, b.w);
    return u.h;
}

__device__ inline uint2 pack4(float4 v) {
    union { fp16x2 h2[2]; uint2 u; } p;
    p.h2[0] = __builtin_amdgcn_cvt_pkrtz(v.x, v.y);
    p.h2[1] = __builtin_amdgcn_cvt_pkrtz(v.z, v.w);
    return p.u;
}

// 8 fp32 -> 8 fp8-e4m3 bytes (ascending order).
__device__ inline uint2 pack8_fp8(float4 a, float4 b) {
    int lo = 0, hi = 0;
    lo = __builtin_amdgcn_cvt_pk_fp8_f32(a.x, a.y, lo, false);
    lo = __builtin_amdgcn_cvt_pk_fp8_f32(a.z, a.w, lo, true);
    hi = __builtin_amdgcn_cvt_pk_fp8_f32(b.x, b.y, hi, false);
    hi = __builtin_amdgcn_cvt_pk_fp8_f32(b.z, b.w, hi, true);
    uint2 r; r.x = (unsigned)lo; r.y = (unsigned)hi; return r;
}

__device__ inline long pack8_fp8_l(const float* p) {
    uint2 b = pack8_fp8(*(const float4*)p, *(const float4*)(p + 4));
    return (long)(((unsigned long)b.y << 32) | b.x);
}

// ---- streaming conversion: both tables -> fp8, into workspace.
__global__ __launch_bounds__(256) void convert_kernel(
    const float4* __restrict__ nci, const float4* __restrict__ fma,
    uint2* __restrict__ nci8, uint2* __restrict__ fma8)
{
    const int stride = gridDim.x * blockDim.x;
    const int tid = blockIdx.x * blockDim.x + threadIdx.x;
    for (int i = tid; i < NCI_ELEMS / 8; i += stride)
        nci8[i] = pack8_fp8(nci[2 * i], nci[2 * i + 1]);
    for (int i = tid; i < FMA_ELEMS / 8; i += stride)
        fma8[i] = pack8_fp8(fma[2 * i], fma[2 * i + 1]);
}

// Issue the 6 independent dwordx4 gathers for one sample-set.
#define GATHER(iN, iM, iF, n01, n23, f01, f23, m01, m23)                     \
    {                                                                        \
        const unsigned char* pn_ = nci8 + (long)(iN) * 64 + hoff;            \
        const unsigned char* pf_ = fma8 + (long)(iF) * 64 + hoff;            \
        const unsigned char* pm_ = nci8 + (long)(iM) * 64 + hoff;            \
        n01 = *(const ulonglong2*)pn_;                                       \
        n23 = *(const ulonglong2*)(pn_ + 16);                                \
        f01 = *(const ulonglong2*)pf_;                                       \
        f23 = *(const ulonglong2*)(pf_ + 16);                                \
        m01 = *(const ulonglong2*)pm_;                                       \
        m23 = *(const ulonglong2*)(pm_ + 16);                                \
    }

// 4 sequential output tiles (one 16-reg accumulator live at a time).
#define COMPUTE_TILES(n01, n23, f01, f23, m01, m23)                          \
    {                                                                        \
        const long An_[4] = {(long)(n01).x, (long)(n01).y,                   \
                             (long)(n23).x, (long)(n23).y};                  \
        const long Ff_[4] = {(long)(f01).x, (long)(f01).y,                   \
                             (long)(f23).x, (long)(f23).y};                  \
        const long Am_[4] = {(long)(m01).x, (long)(m01).y,                   \
                             (long)(m23).x, (long)(m23).y};                  \
        {                                                                    \
            floatx16 a{};                                                    \
            _Pragma("unroll")                                                \
            for (int t = 0; t < 4; ++t)                                      \
                a = __builtin_amdgcn_mfma_f32_32x32x16_fp8_fp8(An_[t], Bn[0][t], a, 0, 0, 0); \
            _Pragma("unroll")                                                \
            for (int t = 0; t < 4; ++t)                                      \
                a = __builtin_amdgcn_mfma_f32_32x32x16_fp8_fp8(Ff_[t], If0[t], a, 0, 0, 0);   \
            _Pragma("unroll")                                                \
            for (int r = 0; r < 16; ++r) loss = fmaf(a[r], a[r], loss);      \
        }                                                                    \
        {                                                                    \
            floatx16 a{};                                                    \
            _Pragma("unroll")                                                \
            for (int t = 0; t < 4; ++t)                                      \
                a = __builtin_amdgcn_mfma_f32_32x32x16_fp8_fp8(An_[t], Bn[1][t], a, 0, 0, 0); \
            _Pragma("unroll")                                                \
            for (int t = 0; t < 4; ++t)                                      \
                a = __builtin_amdgcn_mfma_f32_32x32x16_fp8_fp8(Ff_[t], If1[t], a, 0, 0, 0);   \
            _Pragma("unroll")                                                \
            for (int r = 0; r < 16; ++r) loss = fmaf(a[r], a[r], loss);      \
        }                                                                    \
        {                                                                    \
            floatx16 a{};                                                    \
            _Pragma("unroll")                                                \
            for (int t = 0; t < 4; ++t)                                      \
                a = __builtin_amdgcn_mfma_f32_32x32x16_fp8_fp8(Am_[t], Bm[0][t], a, 0, 0, 0); \
            _Pragma("unroll")                                                \
            for (int t = 0; t < 4; ++t)                                      \
                a = __builtin_amdgcn_mfma_f32_32x32x16_fp8_fp8(Ff_[t], If0[t], a, 0, 0, 0);   \
            _Pragma("unroll")                                                \
            for (int r = 0; r < 16; ++r) loss = fmaf(a[r], a[r], loss);      \
        }                                                                    \
        {                                                                    \
            floatx16 a{};                                                    \
            _Pragma("unroll")                                                \
            for (int t = 0; t < 4; ++t)                                      \
                a = __builtin_amdgcn_mfma_f32_32x32x16_fp8_fp8(Am_[t], Bm[1][t], a, 0, 0, 0); \
            _Pragma("unroll")                                                \
            for (int t = 0; t < 4; ++t)                                      \
                a = __builtin_amdgcn_mfma_f32_32x32x16_fp8_fp8(Ff_[t], If1[t], a, 0, 0, 0);   \
            _Pragma("unroll")                                                \
            for (int r = 0; r < 16; ++r) loss = fmaf(a[r], a[r], loss);      \
        }                                                                    \
    }

// ---- main kernel.
__global__ __launch_bounds__(256, 3) void ontomap_kernel_q(
    const int* __restrict__ pos_n, const int* __restrict__ pos_m,
    const int* __restrict__ pos_f,
    const unsigned char* __restrict__ nci8, const unsigned char* __restrict__ fma8,
    const float* __restrict__ n2f, const float* __restrict__ m2f,
    float* __restrict__ out, int iters)
{
    const int lane = threadIdx.x & 63;
    const int wave = threadIdx.x >> 6;
    const int l31  = lane & 31;
    const int hi   = lane >> 5;
    const int hoff = hi * 32;     // this lane's contiguous 32-byte half-row

    // B fragments under the K-remap k = hoff + t*8 + j.
    long Bn[2][4], Bm[2][4];
#pragma unroll
    for (int nt = 0; nt < 2; ++nt) {
#pragma unroll
        for (int t = 0; t < 4; ++t) {
            Bn[nt][t] = pack8_fp8_l(n2f + (nt * 32 + l31) * 64 + hoff + t * 8);
            Bm[nt][t] = pack8_fp8_l(m2f + (nt * 32 + l31) * 64 + hoff + t * 8);
        }
    }

    // -I fragments (fp8 0xB8 = -1.0 e4m3), verified in rounds 9/10.
    long If0[4], If1[4];
#pragma unroll
    for (int t = 0; t < 4; ++t) {
        const unsigned j = (unsigned)(l31 - t * 8);
        const long pat = (j < 8) ? (long)(0xB8ULL << (8 * j)) : 0L;
        If0[t] = hi ? 0L : pat;
        If1[t] = hi ? pat : 0L;
    }

    float loss = 0.0f;

    const int base  = blockIdx.x * SPB + wave * 32 + l31;
    const int istep = NBLOCKS * SPB;
    const int last  = iters - 1;

    // ---- pipeline fill: stage sets 0 and 1; indices for 2 and 3.
    int iNa = pos_n[base], iMa = pos_m[base], iFa = pos_f[base];
    int s1 = istep + base;
    int iNb = pos_n[s1], iMb = pos_m[s1], iFb = pos_f[s1];

    ulonglong2 An01, An23, Af01, Af23, Am01, Am23;   // set 0
    ulonglong2 Bn01, Bn23, Bf01, Bf23, Bm01, Bm23;   // set 1
    GATHER(iNa, iMa, iFa, An01, An23, Af01, Af23, Am01, Am23);
    GATHER(iNb, iMb, iFb, Bn01, Bn23, Bf01, Bf23, Bm01, Bm23);

    {
        int s = min(2, last) * istep + base;
        iNa = pos_n[s]; iMa = pos_m[s]; iFa = pos_f[s];
        s = min(3, last) * istep + base;
        iNb = pos_n[s]; iMb = pos_m[s]; iFb = pos_f[s];
    }

#pragma unroll 1
    for (int it = 0; it < iters; it += 2) {
        // even iteration: compute set 0, then refill it for it+2.
        COMPUTE_TILES(An01, An23, Af01, Af23, Am01, Am23);
        GATHER(iNa, iMa, iFa, An01, An23, Af01, Af23, Am01, Am23);
        {
            int s = min(it + 4, last) * istep + base;
            iNa = pos_n[s]; iMa = pos_m[s]; iFa = pos_f[s];
        }
        // odd iteration: compute set 1, refill for it+3.
        COMPUTE_TILES(Bn01, Bn23, Bf01, Bf23, Bm01, Bm23);
        GATHER(iNb, iMb, iFb, Bn01, Bn23, Bf01, Bf23, Bm01, Bm23);
        {
            int s = min(it + 5, last) * istep + base;
            iNb = pos_n[s]; iMb = pos_m[s]; iFb = pos_f[s];
        }
    }

#pragma unroll
    for (int o = 32; o > 0; o >>= 1) loss += __shfl_xor(loss, o, 64);
    if (lane == 0) atomicAdd(out, loss);
}

// ---- fallback: fp32 tables with LDS staging (round-4 style), if ws too small.
#define ROW_BYTES 144
__global__ __launch_bounds__(256, 2) void ontomap_kernel_f32(
    const int* __restrict__ pos_n, const int* __restrict__ pos_m,
    const int* __restrict__ pos_f,
    const float* __restrict__ nci, const float* __restrict__ fma_emb,
    const float* __restrict__ n2f, const float* __restrict__ m2f,
    float* __restrict__ out, int iters)
{
    __shared__ char lds[4 * 2 * 32 * ROW_BYTES];

    const int lane = threadIdx.x & 63;
    const int wave = threadIdx.x >> 6;
    const int l31  = lane & 31;
    const int hi   = lane >> 5;
    const int kbase = hi * 8;
    const int srow   = lane >> 4;
    const int schunk = lane & 15;

    char* const nbase = lds + wave * (2 * 32 * ROW_BYTES);
    char* const mbase = nbase + 32 * ROW_BYTES;

    half8 Bn[2][4], Bm[2][4];
#pragma unroll
    for (int nt = 0; nt < 2; ++nt) {
#pragma unroll
        for (int t = 0; t < 4; ++t) {
            const float* p = n2f + (nt * 32 + l31) * 64 + t * 16 + kbase;
            Bn[nt][t] = cvt8(*(const float4*)p, *(const float4*)(p + 4));
            const float* q = m2f + (nt * 32 + l31) * 64 + t * 16 + kbase;
            Bm[nt][t] = cvt8(*(const float4*)q, *(const float4*)(q + 4));
        }
    }

    float loss = 0.0f;
    int in_, im_, if_;
    {
        int s = blockIdx.x * SPB + wave * 32 + l31;
        in_ = pos_n[s]; im_ = pos_m[s]; if_ = pos_f[s];
    }

#pragma unroll 1
    for (int it = 0; it < iters; ++it) {
        const int in0 = in_, im0 = im_, if0 = if_;
        if (it + 1 < iters) {
            int s = ((it + 1) * NBLOCKS + blockIdx.x) * SPB + wave * 32 + l31;
            in_ = pos_n[s]; im_ = pos_m[s]; if_ = pos_f[s];
        }

#pragma unroll
        for (int i = 0; i < 8; ++i) {
            const int rl = i * 4 + srow;
            const int rn = __shfl(in0, rl, 64);
            float4 v = ((const float4*)(nci + (long)rn * 64))[schunk];
            *(uint2*)(nbase + rl * ROW_BYTES + schunk * 8) = pack4(v);
            const int rm = __shfl(im0, rl, 64);
            float4 w = ((const float4*)(nci + (long)rm * 64))[schunk];
            *(uint2*)(mbase + rl * ROW_BYTES + schunk * 8) = pack4(w);
        }
        asm volatile("" ::: "memory");

        floatx16 aN0{}, aN1{}, aM0{}, aM1{};
#pragma unroll
        for (int t = 0; t < 4; ++t) {
            half8 aF = *(const half8*)(nbase + l31 * ROW_BYTES + t * 32 + hi * 16);
            aN0 = __builtin_amdgcn_mfma_f32_32x32x16_f16(aF, Bn[0][t], aN0, 0, 0, 0);
            aN1 = __builtin_amdgcn_mfma_f32_32x32x16_f16(aF, Bn[1][t], aN1, 0, 0, 0);
            half8 bF = *(const half8*)(mbase + l31 * ROW_BYTES + t * 32 + hi * 16);
            aM0 = __builtin_amdgcn_mfma_f32_32x32x16_f16(bF, Bm[0][t], aM0, 0, 0, 0);
            aM1 = __builtin_amdgcn_mfma_f32_32x32x16_f16(bF, Bm[1][t], aM1, 0, 0, 0);
        }

#pragma unroll
        for (int r = 0; r < 16; ++r) {
            const int mrow = (r & 3) + 8 * (r >> 2) + 4 * hi;
            const int fid  = __shfl(if0, mrow, 64);
            const float* pf = fma_emb + (long)fid * 64 + l31;
            const float f0 = pf[0];
            const float f1 = pf[32];
            float d;
            d = aN0[r] - f0; loss = fmaf(d, d, loss);
            d = aM0[r] - f0; loss = fmaf(d, d, loss);
            d = aN1[r] - f1; loss = fmaf(d, d, loss);
            d = aM1[r] - f1; loss = fmaf(d, d, loss);
        }
    }

#pragma unroll
    for (int o = 32; o > 0; o >>= 1) loss += __shfl_xor(loss, o, 64);
    if (lane == 0) atomicAdd(out, loss);
}

extern "C" void kernel_launch(void* const* d_in, const int* in_sizes, int n_in,
                              void* d_out, int out_size, void* d_ws, size_t ws_size,
                              hipStream_t stream) {
    const int*   pos_n   = (const int*)d_in[0];
    const int*   pos_m   = (const int*)d_in[1];
    const int*   pos_f   = (const int*)d_in[2];
    const float* nci_emb = (const float*)d_in[3];
    const float* fma_emb = (const float*)d_in[4];
    const float* n2f_mat = (const float*)d_in[5];
    const float* m2f_mat = (const float*)d_in[6];
    float* out = (float*)d_out;

    const int B = in_sizes[0];
    const int iters = B / (NBLOCKS * SPB);  // 1,048,576 -> 8

    (void)hipMemsetAsync(out, 0, sizeof(float), stream);

    const size_t need = (size_t)NCI_ELEMS + (size_t)FMA_ELEMS;  // 16 MB
    if (ws_size >= need) {
        unsigned char* nci8 = (unsigned char*)d_ws;
        unsigned char* fma8 = nci8 + NCI_ELEMS;   // 9,600,000 is 64B-aligned
        convert_kernel<<<2048, 256, 0, stream>>>(
            (const float4*)nci_emb, (const float4*)fma_emb,
            (uint2*)nci8, (uint2*)fma8);
        ontomap_kernel_q<<<NBLOCKS, 256, 0, stream>>>(
            pos_n, pos_m, pos_f, nci8, fma8, n2f_mat, m2f_mat, out, iters);
    } else {
        ontomap_kernel_f32<<<NBLOCKS, 256, 0, stream>>>(
            pos_n, pos_m, pos_f, nci_emb, fma_emb, n2f_mat, m2f_mat, out, iters);
    }
}